// Round 5
// baseline (390.347 us; speedup 1.0000x reference)
//
#include <hip/hip_runtime.h>
#include <math.h>

// Problem constants (fixed shapes from setup_inputs)
#define NCLS   19
#define HW     (512*1024)          // 524288 per-image plane
#define BHW    (8*HW)              // 4194304 pixels
#define NQ     (BHW/4)             // 1048576 float4 quads
#define GRID_Q (NQ/256)            // 4096 blocks
#define KSEL   262144u             // N_MIN
#define THRESH 0.35667494393873245f

struct Meta {
  double S;                 // sum of losses > THRESH
  unsigned int K;           // count of losses > THRESH
  unsigned int done0;       // last-block counter, k_hist_weights
  unsigned int done1;       // last-block counter, k_loss
  unsigned int _pad;
  unsigned int counts[32];  // label histogram
  float weights[32];        // ENet class weights
};

// ---------- label histogram + ENet weights (last-block fused) ----------
__global__ __launch_bounds__(256) void k_hist_weights(const int* __restrict__ lab,
                                                      Meta* __restrict__ m) {
  __shared__ unsigned int h[32];
  if (threadIdx.x < 32) h[threadIdx.x] = 0u;
  __syncthreads();
  int q = blockIdx.x * 256 + threadIdx.x;       // grid covers NQ exactly
  int4 l = reinterpret_cast<const int4*>(lab)[q];
  atomicAdd(&h[l.x], 1u);
  atomicAdd(&h[l.y], 1u);
  atomicAdd(&h[l.z], 1u);
  atomicAdd(&h[l.w], 1u);
  __syncthreads();
  if (threadIdx.x < 32) {
    unsigned int c = h[threadIdx.x];
    if (c) atomicAdd(&m->counts[threadIdx.x], c);
  }
  // __syncthreads (s_waitcnt before s_barrier) guarantees this block's global
  // atomics are complete before the done-counter bump below.
  __syncthreads();
  if (threadIdx.x == 0) {
    __threadfence();
    unsigned int done = atomicAdd(&m->done0, 1u);
    if (done == GRID_Q - 1u) {
      // All blocks' count atomics are globally visible. Read coherently.
      for (int c = 0; c < NCLS; ++c) {
        unsigned int cnt = atomicAdd(&m->counts[c], 0u);
        float p = (float)cnt * (1.0f / (float)BHW);
        m->weights[c] = 1.0f / logf(1.02f + p);
      }
    }
  }
}

// ---------- fused weighted-CE loss + S/K + common-path finalize ----------
__global__ __launch_bounds__(256) void k_loss(const float* __restrict__ logits,
                                              const int* __restrict__ lab,
                                              float* __restrict__ loss,
                                              Meta* __restrict__ m,
                                              float* __restrict__ out) {
  __shared__ float w[NCLS];
  __shared__ float sp[4];
  __shared__ unsigned int cp[4];
  if (threadIdx.x < NCLS) w[threadIdx.x] = m->weights[threadIdx.x];
  __syncthreads();

  int q = blockIdx.x * 256 + threadIdx.x;       // quad index, grid covers NQ
  int base = q << 2;
  int b  = base >> 19;                          // / HW (2^19)
  int hw = base & (HW - 1);
  const float* lp = logits + (long)b * (NCLS * HW) + hw;
  int4 l4 = reinterpret_cast<const int4*>(lab)[q];

  float4 vals[NCLS];
#pragma unroll
  for (int c = 0; c < NCLS; ++c) {
    vals[c] = *reinterpret_cast<const float4*>(lp);
    lp += HW;
  }

  float m0 = -INFINITY, m1 = -INFINITY, m2 = -INFINITY, m3 = -INFINITY;
#pragma unroll
  for (int c = 0; c < NCLS; ++c) {
    m0 = fmaxf(m0, vals[c].x); m1 = fmaxf(m1, vals[c].y);
    m2 = fmaxf(m2, vals[c].z); m3 = fmaxf(m3, vals[c].w);
  }
  float s0 = 0.f, s1 = 0.f, s2 = 0.f, s3 = 0.f;
  float x0 = 0.f, x1 = 0.f, x2 = 0.f, x3 = 0.f;
#pragma unroll
  for (int c = 0; c < NCLS; ++c) {
    float4 v = vals[c];
    s0 += __expf(v.x - m0); s1 += __expf(v.y - m1);
    s2 += __expf(v.z - m2); s3 += __expf(v.w - m3);
    x0 = (c == l4.x) ? v.x : x0;
    x1 = (c == l4.y) ? v.y : x1;
    x2 = (c == l4.z) ? v.z : x2;
    x3 = (c == l4.w) ? v.w : x3;
  }
  float4 o;
  o.x = w[l4.x] * (m0 + logf(s0) - x0);
  o.y = w[l4.y] * (m1 + logf(s1) - x1);
  o.z = w[l4.z] * (m2 + logf(s2) - x2);
  o.w = w[l4.w] * (m3 + logf(s3) - x3);
  reinterpret_cast<float4*>(loss)[q] = o;      // needed only by fallback path

  float ls = 0.f; unsigned int lc = 0u;
  if (o.x > THRESH) { ls += o.x; ++lc; }
  if (o.y > THRESH) { ls += o.y; ++lc; }
  if (o.z > THRESH) { ls += o.z; ++lc; }
  if (o.w > THRESH) { ls += o.w; ++lc; }
#pragma unroll
  for (int off = 32; off > 0; off >>= 1) {
    ls += __shfl_down(ls, off);
    lc += __shfl_down(lc, off);
  }
  int wid = threadIdx.x >> 6;
  if ((threadIdx.x & 63) == 0) { sp[wid] = ls; cp[wid] = lc; }
  __syncthreads();
  if (threadIdx.x == 0) {
    float bs = sp[0] + sp[1] + sp[2] + sp[3];
    unsigned int bc = cp[0] + cp[1] + cp[2] + cp[3];
    atomicAdd(&m->S, (double)bs);
    atomicAdd(&m->K, bc);
    __threadfence();                            // drain S/K before done bump
    unsigned int done = atomicAdd(&m->done1, 1u);
    if (done == GRID_Q - 1u) {
      double S = atomicAdd(&m->S, 0.0);
      unsigned int K = atomicAdd(&m->K, 0u);
      if (K > KSEL) out[0] = (float)(S / (double)K);   // common path: done here
    }
  }
}

// ---------- rare-path fallback: single-WG 3-level radix select ----------
// Only does real work when K <= KSEL (never on the bench data). One workgroup
// so all level-to-level dependencies are plain __syncthreads.
__global__ __launch_bounds__(1024) void k_fallback(const float* __restrict__ loss,
                                                   const Meta* __restrict__ m,
                                                   float* __restrict__ out) {
  __shared__ unsigned int h[2048];
  __shared__ unsigned int sel[4];   // b1, b2, vbits, k-remaining
  __shared__ double dsp[16];
  __shared__ unsigned int dcp[16];

  unsigned int K = m->K;
  if (K > KSEL) return;             // common path: nothing to do

  const int T = 1024;
  int tid = threadIdx.x;

  // ---- level 1: bits[31:21] ----
  for (int i = tid; i < 2048; i += T) h[i] = 0u;
  __syncthreads();
  for (int q = tid; q < NQ; q += T) {
    float4 v = reinterpret_cast<const float4*>(loss)[q];
    atomicAdd(&h[__float_as_uint(v.x) >> 21], 1u);
    atomicAdd(&h[__float_as_uint(v.y) >> 21], 1u);
    atomicAdd(&h[__float_as_uint(v.z) >> 21], 1u);
    atomicAdd(&h[__float_as_uint(v.w) >> 21], 1u);
  }
  __syncthreads();
  if (tid == 0) {
    unsigned int cum = 0;
    for (int b = 2047; b >= 0; --b) {
      unsigned int hb = h[b];
      if (cum + hb >= KSEL) { sel[0] = (unsigned)b; sel[3] = KSEL - cum; break; }
      cum += hb;
    }
  }
  __syncthreads();
  unsigned int b1 = sel[0], k1 = sel[3];

  // ---- level 2: bits[20:10] within b1 ----
  for (int i = tid; i < 2048; i += T) h[i] = 0u;
  __syncthreads();
  for (int q = tid; q < NQ; q += T) {
    float4 v = reinterpret_cast<const float4*>(loss)[q];
    unsigned int bx = __float_as_uint(v.x), by = __float_as_uint(v.y);
    unsigned int bz = __float_as_uint(v.z), bw = __float_as_uint(v.w);
    if ((bx >> 21) == b1) atomicAdd(&h[(bx >> 10) & 2047u], 1u);
    if ((by >> 21) == b1) atomicAdd(&h[(by >> 10) & 2047u], 1u);
    if ((bz >> 21) == b1) atomicAdd(&h[(bz >> 10) & 2047u], 1u);
    if ((bw >> 21) == b1) atomicAdd(&h[(bw >> 10) & 2047u], 1u);
  }
  __syncthreads();
  if (tid == 0) {
    unsigned int cum = 0;
    for (int b = 2047; b >= 0; --b) {
      unsigned int hb = h[b];
      if (cum + hb >= k1) { sel[1] = (unsigned)b; sel[3] = k1 - cum; break; }
      cum += hb;
    }
  }
  __syncthreads();
  unsigned int b2 = sel[1], k2 = sel[3];
  unsigned int pre = (b1 << 11) | b2;

  // ---- level 3: bits[9:0] within (b1,b2) ----
  for (int i = tid; i < 1024; i += T) h[i] = 0u;
  __syncthreads();
  for (int q = tid; q < NQ; q += T) {
    float4 v = reinterpret_cast<const float4*>(loss)[q];
    unsigned int bx = __float_as_uint(v.x), by = __float_as_uint(v.y);
    unsigned int bz = __float_as_uint(v.z), bw = __float_as_uint(v.w);
    if ((bx >> 10) == pre) atomicAdd(&h[bx & 1023u], 1u);
    if ((by >> 10) == pre) atomicAdd(&h[by & 1023u], 1u);
    if ((bz >> 10) == pre) atomicAdd(&h[bz & 1023u], 1u);
    if ((bw >> 10) == pre) atomicAdd(&h[bw & 1023u], 1u);
  }
  __syncthreads();
  if (tid == 0) {
    unsigned int cum = 0;
    for (int b = 1023; b >= 0; --b) {
      unsigned int hb = h[b];
      if (cum + hb >= k2) { sel[2] = (b1 << 21) | (b2 << 10) | (unsigned)b; break; }
      cum += hb;
    }
  }
  __syncthreads();
  unsigned int vb = sel[2];

  // ---- sum & count of loss strictly greater than v ----
  double ls = 0.0; unsigned int lc = 0u;
  for (int q = tid; q < NQ; q += T) {
    float4 v = reinterpret_cast<const float4*>(loss)[q];
    if (__float_as_uint(v.x) > vb) { ls += (double)v.x; ++lc; }
    if (__float_as_uint(v.y) > vb) { ls += (double)v.y; ++lc; }
    if (__float_as_uint(v.z) > vb) { ls += (double)v.z; ++lc; }
    if (__float_as_uint(v.w) > vb) { ls += (double)v.w; ++lc; }
  }
#pragma unroll
  for (int off = 32; off > 0; off >>= 1) {
    ls += __shfl_down(ls, off);
    lc += __shfl_down(lc, off);
  }
  int wid = tid >> 6;
  if ((tid & 63) == 0) { dsp[wid] = ls; dcp[wid] = lc; }
  __syncthreads();
  if (tid == 0) {
    double sumV = 0.0; unsigned int cntV = 0u;
    for (int i = 0; i < 16; ++i) { sumV += dsp[i]; cntV += dcp[i]; }
    float v = __uint_as_float(vb);
    double top = sumV + (double)(KSEL - cntV) * (double)v;
    out[0] = (float)(top / (double)KSEL);
  }
}

extern "C" void kernel_launch(void* const* d_in, const int* in_sizes, int n_in,
                              void* d_out, int out_size, void* d_ws, size_t ws_size,
                              hipStream_t stream) {
  const float* logits = (const float*)d_in[0];
  const int*   labels = (const int*)d_in[1];
  float* out  = (float*)d_out;
  float* loss = (float*)d_ws;                           // 16 MiB per-pixel losses
  Meta*  meta = (Meta*)((char*)d_ws + (size_t)BHW * 4); // metadata after loss array

  hipMemsetAsync(meta, 0, sizeof(Meta), stream);        // ~300 B: re-zero accumulators
  k_hist_weights<<<GRID_Q, 256, 0, stream>>>(labels, meta);
  k_loss        <<<GRID_Q, 256, 0, stream>>>(logits, labels, loss, meta, out);
  k_fallback    <<<1, 1024, 0, stream>>>(loss, meta, out);
}

// Round 6
// 213.420 us; speedup vs baseline: 1.8290x; 1.8290x over previous
//
#include <hip/hip_runtime.h>
#include <math.h>

// Problem constants (fixed shapes from setup_inputs)
#define NCLS   19
#define HW     (512*1024)          // 524288 per-image plane
#define BHW    (8*HW)              // 4194304 pixels
#define NQ     (BHW/4)             // 1048576 int4 quads (labels)
#define GRID_H (NQ/256)            // 4096 blocks for label hist
#define GRID_L (BHW/256)           // 16384 blocks for loss (1 pixel/thread)
#define NSLOT  64                  // partial-sum slots
#define KSEL   262144u             // N_MIN
#define THRESH 0.35667494393873245f

struct Meta {
  double Spart[NSLOT];        // partial sums of losses > THRESH
  unsigned int Kpart[NSLOT];  // partial counts of losses > THRESH
  unsigned int done0;         // last-block counter, k_hist_weights
  unsigned int _pad[3];
  unsigned int counts[32];    // label histogram
  float weights[32];          // ENet class weights
};

// ---------- label histogram + ENet weights (last-block fused) ----------
__global__ __launch_bounds__(256) void k_hist_weights(const int* __restrict__ lab,
                                                      Meta* __restrict__ m) {
  __shared__ unsigned int h[32];
  if (threadIdx.x < 32) h[threadIdx.x] = 0u;
  __syncthreads();
  int q = blockIdx.x * 256 + threadIdx.x;       // grid covers NQ exactly
  int4 l = reinterpret_cast<const int4*>(lab)[q];
  atomicAdd(&h[l.x], 1u);
  atomicAdd(&h[l.y], 1u);
  atomicAdd(&h[l.z], 1u);
  atomicAdd(&h[l.w], 1u);
  __syncthreads();
  if (threadIdx.x < 32) {
    unsigned int c = h[threadIdx.x];
    if (c) atomicAdd(&m->counts[threadIdx.x], c);
  }
  __syncthreads();
  if (threadIdx.x == 0) {
    __threadfence();
    unsigned int done = atomicAdd(&m->done0, 1u);
    if (done == GRID_H - 1u) {
      // All blocks' count atomics are globally visible; compute weights once.
      for (int c = 0; c < NCLS; ++c) {
        unsigned int cnt = atomicAdd(&m->counts[c], 0u);
        float p = (float)cnt * (1.0f / (float)BHW);
        m->weights[c] = 1.0f / logf(1.02f + p);
      }
    }
  }
}

// ---------- fused weighted-CE loss, 1 pixel/thread (no spills) ----------
__global__ __launch_bounds__(256) void k_loss(const float* __restrict__ logits,
                                              const int* __restrict__ lab,
                                              float* __restrict__ loss,
                                              Meta* __restrict__ m) {
  __shared__ float w[NCLS];
  __shared__ float sp[4];
  __shared__ unsigned int cp[4];
  if (threadIdx.x < NCLS) w[threadIdx.x] = m->weights[threadIdx.x];
  __syncthreads();

  int p  = blockIdx.x * 256 + threadIdx.x;      // pixel index, grid covers BHW
  int b  = p >> 19;                             // / HW (2^19)
  int hw = p & (HW - 1);
  const float* lp = logits + (size_t)b * (NCLS * HW) + hw;
  int lbl = lab[p];

  float v[NCLS];
#pragma unroll
  for (int c = 0; c < NCLS; ++c) v[c] = lp[c * HW];   // 19 coalesced streams

  float mx = v[0];
#pragma unroll
  for (int c = 1; c < NCLS; ++c) mx = fmaxf(mx, v[c]);

  float s = 0.f, x = 0.f;
#pragma unroll
  for (int c = 0; c < NCLS; ++c) {
    s += __expf(v[c] - mx);
    x = (c == lbl) ? v[c] : x;
  }
  float o = w[lbl] * (mx + logf(s) - x);
  loss[p] = o;                                  // needed only by fallback path

  float ls = (o > THRESH) ? o : 0.f;
  unsigned int lc = (o > THRESH) ? 1u : 0u;
#pragma unroll
  for (int off = 32; off > 0; off >>= 1) {
    ls += __shfl_down(ls, off);
    lc += __shfl_down(lc, off);
  }
  int wid = threadIdx.x >> 6;
  if ((threadIdx.x & 63) == 0) { sp[wid] = ls; cp[wid] = lc; }
  __syncthreads();
  if (threadIdx.x == 0) {
    float bs = sp[0] + sp[1] + sp[2] + sp[3];
    unsigned int bc = cp[0] + cp[1] + cp[2] + cp[3];
    int slot = blockIdx.x & (NSLOT - 1);
    atomicAdd(&m->Spart[slot], (double)bs);
    atomicAdd(&m->Kpart[slot], bc);
  }
}

// ---------- finalize: common path trivial; rare path = radix select ----------
__global__ __launch_bounds__(1024) void k_final(const float* __restrict__ loss,
                                                Meta* __restrict__ m,
                                                float* __restrict__ out) {
  __shared__ unsigned int h[2048];
  __shared__ unsigned int sel[4];   // b1, b2, vbits, k-remaining
  __shared__ double dsp[16];
  __shared__ unsigned int dcp[16];

  const int T = 1024;
  int tid = threadIdx.x;

  // Reduce the 64 partial slots (single wave does it; tiny).
  __shared__ double Stot_s; __shared__ unsigned int Ktot_s;
  if (tid == 0) {
    double S = 0.0; unsigned int K = 0u;
    for (int i = 0; i < NSLOT; ++i) { S += m->Spart[i]; K += m->Kpart[i]; }
    Stot_s = S; Ktot_s = K;
    if (K > KSEL) out[0] = (float)(S / (double)K);  // common path: done
  }
  __syncthreads();
  unsigned int K = Ktot_s;
  if (K > KSEL) return;

  // ---- rare path: exact top-KSEL via 3-level radix select over loss bits ----
  // level 1: bits[31:21]
  for (int i = tid; i < 2048; i += T) h[i] = 0u;
  __syncthreads();
  for (int q = tid; q < NQ; q += T) {
    float4 v = reinterpret_cast<const float4*>(loss)[q];
    atomicAdd(&h[__float_as_uint(v.x) >> 21], 1u);
    atomicAdd(&h[__float_as_uint(v.y) >> 21], 1u);
    atomicAdd(&h[__float_as_uint(v.z) >> 21], 1u);
    atomicAdd(&h[__float_as_uint(v.w) >> 21], 1u);
  }
  __syncthreads();
  if (tid == 0) {
    unsigned int cum = 0;
    for (int b = 2047; b >= 0; --b) {
      unsigned int hb = h[b];
      if (cum + hb >= KSEL) { sel[0] = (unsigned)b; sel[3] = KSEL - cum; break; }
      cum += hb;
    }
  }
  __syncthreads();
  unsigned int b1 = sel[0], k1 = sel[3];

  // level 2: bits[20:10] within b1
  for (int i = tid; i < 2048; i += T) h[i] = 0u;
  __syncthreads();
  for (int q = tid; q < NQ; q += T) {
    float4 v = reinterpret_cast<const float4*>(loss)[q];
    unsigned int bx = __float_as_uint(v.x), by = __float_as_uint(v.y);
    unsigned int bz = __float_as_uint(v.z), bw = __float_as_uint(v.w);
    if ((bx >> 21) == b1) atomicAdd(&h[(bx >> 10) & 2047u], 1u);
    if ((by >> 21) == b1) atomicAdd(&h[(by >> 10) & 2047u], 1u);
    if ((bz >> 21) == b1) atomicAdd(&h[(bz >> 10) & 2047u], 1u);
    if ((bw >> 21) == b1) atomicAdd(&h[(bw >> 10) & 2047u], 1u);
  }
  __syncthreads();
  if (tid == 0) {
    unsigned int cum = 0;
    for (int b = 2047; b >= 0; --b) {
      unsigned int hb = h[b];
      if (cum + hb >= k1) { sel[1] = (unsigned)b; sel[3] = k1 - cum; break; }
      cum += hb;
    }
  }
  __syncthreads();
  unsigned int b2 = sel[1], k2 = sel[3];
  unsigned int pre = (b1 << 11) | b2;

  // level 3: bits[9:0] within (b1,b2)
  for (int i = tid; i < 1024; i += T) h[i] = 0u;
  __syncthreads();
  for (int q = tid; q < NQ; q += T) {
    float4 v = reinterpret_cast<const float4*>(loss)[q];
    unsigned int bx = __float_as_uint(v.x), by = __float_as_uint(v.y);
    unsigned int bz = __float_as_uint(v.z), bw = __float_as_uint(v.w);
    if ((bx >> 10) == pre) atomicAdd(&h[bx & 1023u], 1u);
    if ((by >> 10) == pre) atomicAdd(&h[by & 1023u], 1u);
    if ((bz >> 10) == pre) atomicAdd(&h[bz & 1023u], 1u);
    if ((bw >> 10) == pre) atomicAdd(&h[bw & 1023u], 1u);
  }
  __syncthreads();
  if (tid == 0) {
    unsigned int cum = 0;
    for (int b = 1023; b >= 0; --b) {
      unsigned int hb = h[b];
      if (cum + hb >= k2) { sel[2] = (b1 << 21) | (b2 << 10) | (unsigned)b; break; }
      cum += hb;
    }
  }
  __syncthreads();
  unsigned int vb = sel[2];

  // sum & count of loss strictly greater than pivot v
  double ls = 0.0; unsigned int lc = 0u;
  for (int q = tid; q < NQ; q += T) {
    float4 v = reinterpret_cast<const float4*>(loss)[q];
    if (__float_as_uint(v.x) > vb) { ls += (double)v.x; ++lc; }
    if (__float_as_uint(v.y) > vb) { ls += (double)v.y; ++lc; }
    if (__float_as_uint(v.z) > vb) { ls += (double)v.z; ++lc; }
    if (__float_as_uint(v.w) > vb) { ls += (double)v.w; ++lc; }
  }
#pragma unroll
  for (int off = 32; off > 0; off >>= 1) {
    ls += __shfl_down(ls, off);
    lc += __shfl_down(lc, off);
  }
  int wid = tid >> 6;
  if ((tid & 63) == 0) { dsp[wid] = ls; dcp[wid] = lc; }
  __syncthreads();
  if (tid == 0) {
    double sumV = 0.0; unsigned int cntV = 0u;
    for (int i = 0; i < 16; ++i) { sumV += dsp[i]; cntV += dcp[i]; }
    float v = __uint_as_float(vb);
    double top = sumV + (double)(KSEL - cntV) * (double)v;
    out[0] = (float)(top / (double)KSEL);
  }
}

extern "C" void kernel_launch(void* const* d_in, const int* in_sizes, int n_in,
                              void* d_out, int out_size, void* d_ws, size_t ws_size,
                              hipStream_t stream) {
  const float* logits = (const float*)d_in[0];
  const int*   labels = (const int*)d_in[1];
  float* out  = (float*)d_out;
  float* loss = (float*)d_ws;                           // 16 MiB per-pixel losses
  Meta*  meta = (Meta*)((char*)d_ws + (size_t)BHW * 4); // metadata after loss array

  hipMemsetAsync(meta, 0, sizeof(Meta), stream);        // re-zero accumulators
  k_hist_weights<<<GRID_H, 256, 0, stream>>>(labels, meta);
  k_loss        <<<GRID_L, 256, 0, stream>>>(logits, labels, loss, meta);
  k_final       <<<1, 1024, 0, stream>>>(loss, meta, out);
}

// Round 7
// 201.093 us; speedup vs baseline: 1.9411x; 1.0613x over previous
//
#include <hip/hip_runtime.h>
#include <math.h>

// Problem constants (fixed shapes from setup_inputs)
#define NCLS   19
#define HW     (512*1024)          // 524288 per-image plane
#define BHW    (8*HW)              // 4194304 pixels
#define NQ     (BHW/4)             // 1048576 quads
#define GRID_Q (NQ/256)            // 4096 blocks (4 px/thread)
#define NSLOT  64                  // partial-sum slots
#define KSEL   262144u             // N_MIN
#define THRESH 0.35667494393873245f

struct Meta {
  double Spart[NSLOT];        // partial sums of losses > THRESH
  unsigned int Kpart[NSLOT];  // partial counts of losses > THRESH
  unsigned int done0;         // last-block counter, k_hist_weights
  unsigned int _pad[3];
  unsigned int counts[32];    // label histogram
  float weights[32];          // ENet class weights
};

// ---------- zero the accumulators (replaces hipMemsetAsync graph node) ----------
__global__ __launch_bounds__(256) void k_init(Meta* __restrict__ m) {
  unsigned int* p = (unsigned int*)m;
  const int n = (int)(sizeof(Meta) / 4);
  for (int i = threadIdx.x; i < n; i += 256) p[i] = 0u;
}

// ---------- label histogram + ENet weights (last-block fused) ----------
__global__ __launch_bounds__(256) void k_hist_weights(const int* __restrict__ lab,
                                                      Meta* __restrict__ m) {
  __shared__ unsigned int h[32];
  if (threadIdx.x < 32) h[threadIdx.x] = 0u;
  __syncthreads();
  int q = blockIdx.x * 256 + threadIdx.x;       // grid covers NQ exactly
  int4 l = reinterpret_cast<const int4*>(lab)[q];
  atomicAdd(&h[l.x], 1u);
  atomicAdd(&h[l.y], 1u);
  atomicAdd(&h[l.z], 1u);
  atomicAdd(&h[l.w], 1u);
  __syncthreads();
  if (threadIdx.x < 32) {
    unsigned int c = h[threadIdx.x];
    if (c) atomicAdd(&m->counts[threadIdx.x], c);
  }
  __syncthreads();
  if (threadIdx.x == 0) {
    __threadfence();
    unsigned int done = atomicAdd(&m->done0, 1u);
    if (done == GRID_Q - 1u) {
      for (int c = 0; c < NCLS; ++c) {
        unsigned int cnt = atomicAdd(&m->counts[c], 0u);
        float p = (float)cnt * (1.0f / (float)BHW);
        m->weights[c] = 1.0f / logf(1.02f + p);
      }
    }
  }
}

// ---------- fused weighted-CE loss: float4 online softmax, ~30 VGPRs ----------
__global__ __launch_bounds__(256, 8) void k_loss(const float* __restrict__ logits,
                                                 const int* __restrict__ lab,
                                                 float* __restrict__ loss,
                                                 Meta* __restrict__ m) {
  __shared__ float w[NCLS];
  __shared__ float sp[4];
  __shared__ unsigned int cp[4];
  if (threadIdx.x < NCLS) w[threadIdx.x] = m->weights[threadIdx.x];
  __syncthreads();

  int q = blockIdx.x * 256 + threadIdx.x;       // quad index, grid covers NQ
  int base = q << 2;
  int b  = base >> 19;                          // / HW (2^19)
  int hw = base & (HW - 1);
  const float* lp = logits + (size_t)b * (NCLS * HW) + hw;
  int4 l4 = reinterpret_cast<const int4*>(lab)[q];

  // class 0 initializes the online state
  float4 v = *reinterpret_cast<const float4*>(lp);
  float m0 = v.x, m1 = v.y, m2 = v.z, m3 = v.w;
  float s0 = 1.f, s1 = 1.f, s2 = 1.f, s3 = 1.f;
  float x0 = (l4.x == 0) ? v.x : 0.f;
  float x1 = (l4.y == 0) ? v.y : 0.f;
  float x2 = (l4.z == 0) ? v.z : 0.f;
  float x3 = (l4.w == 0) ? v.w : 0.f;

#pragma unroll
  for (int c = 1; c < NCLS; ++c) {
    lp += HW;
    float4 t = *reinterpret_cast<const float4*>(lp);
    float nm;
    nm = fmaxf(m0, t.x); s0 = s0 * __expf(m0 - nm) + __expf(t.x - nm); m0 = nm;
    nm = fmaxf(m1, t.y); s1 = s1 * __expf(m1 - nm) + __expf(t.y - nm); m1 = nm;
    nm = fmaxf(m2, t.z); s2 = s2 * __expf(m2 - nm) + __expf(t.z - nm); m2 = nm;
    nm = fmaxf(m3, t.w); s3 = s3 * __expf(m3 - nm) + __expf(t.w - nm); m3 = nm;
    x0 = (c == l4.x) ? t.x : x0;
    x1 = (c == l4.y) ? t.y : x1;
    x2 = (c == l4.z) ? t.z : x2;
    x3 = (c == l4.w) ? t.w : x3;
  }

  float4 o;
  o.x = w[l4.x] * (m0 + logf(s0) - x0);
  o.y = w[l4.y] * (m1 + logf(s1) - x1);
  o.z = w[l4.z] * (m2 + logf(s2) - x2);
  o.w = w[l4.w] * (m3 + logf(s3) - x3);
  reinterpret_cast<float4*>(loss)[q] = o;       // needed only by fallback path

  float ls = 0.f; unsigned int lc = 0u;
  if (o.x > THRESH) { ls += o.x; ++lc; }
  if (o.y > THRESH) { ls += o.y; ++lc; }
  if (o.z > THRESH) { ls += o.z; ++lc; }
  if (o.w > THRESH) { ls += o.w; ++lc; }
#pragma unroll
  for (int off = 32; off > 0; off >>= 1) {
    ls += __shfl_down(ls, off);
    lc += __shfl_down(lc, off);
  }
  int wid = threadIdx.x >> 6;
  if ((threadIdx.x & 63) == 0) { sp[wid] = ls; cp[wid] = lc; }
  __syncthreads();
  if (threadIdx.x == 0) {
    float bs = sp[0] + sp[1] + sp[2] + sp[3];
    unsigned int bc = cp[0] + cp[1] + cp[2] + cp[3];
    int slot = blockIdx.x & (NSLOT - 1);        // 64 contenders/slot
    atomicAdd(&m->Spart[slot], (double)bs);
    atomicAdd(&m->Kpart[slot], bc);
  }
}

// ---------- finalize: common path trivial; rare path = radix select ----------
__global__ __launch_bounds__(1024) void k_final(const float* __restrict__ loss,
                                                Meta* __restrict__ m,
                                                float* __restrict__ out) {
  __shared__ unsigned int h[2048];
  __shared__ unsigned int sel[4];   // b1, b2, vbits, k-remaining
  __shared__ double dsp[16];
  __shared__ unsigned int dcp[16];

  const int T = 1024;
  int tid = threadIdx.x;

  __shared__ unsigned int Ktot_s;
  if (tid == 0) {
    double S = 0.0; unsigned int K = 0u;
    for (int i = 0; i < NSLOT; ++i) { S += m->Spart[i]; K += m->Kpart[i]; }
    Ktot_s = K;
    if (K > KSEL) out[0] = (float)(S / (double)K);  // common path: done
  }
  __syncthreads();
  unsigned int K = Ktot_s;
  if (K > KSEL) return;

  // ---- rare path: exact top-KSEL via 3-level radix select over loss bits ----
  for (int i = tid; i < 2048; i += T) h[i] = 0u;
  __syncthreads();
  for (int q = tid; q < NQ; q += T) {
    float4 v = reinterpret_cast<const float4*>(loss)[q];
    atomicAdd(&h[__float_as_uint(v.x) >> 21], 1u);
    atomicAdd(&h[__float_as_uint(v.y) >> 21], 1u);
    atomicAdd(&h[__float_as_uint(v.z) >> 21], 1u);
    atomicAdd(&h[__float_as_uint(v.w) >> 21], 1u);
  }
  __syncthreads();
  if (tid == 0) {
    unsigned int cum = 0;
    for (int b = 2047; b >= 0; --b) {
      unsigned int hb = h[b];
      if (cum + hb >= KSEL) { sel[0] = (unsigned)b; sel[3] = KSEL - cum; break; }
      cum += hb;
    }
  }
  __syncthreads();
  unsigned int b1 = sel[0], k1 = sel[3];

  for (int i = tid; i < 2048; i += T) h[i] = 0u;
  __syncthreads();
  for (int q = tid; q < NQ; q += T) {
    float4 v = reinterpret_cast<const float4*>(loss)[q];
    unsigned int bx = __float_as_uint(v.x), by = __float_as_uint(v.y);
    unsigned int bz = __float_as_uint(v.z), bw = __float_as_uint(v.w);
    if ((bx >> 21) == b1) atomicAdd(&h[(bx >> 10) & 2047u], 1u);
    if ((by >> 21) == b1) atomicAdd(&h[(by >> 10) & 2047u], 1u);
    if ((bz >> 21) == b1) atomicAdd(&h[(bz >> 10) & 2047u], 1u);
    if ((bw >> 21) == b1) atomicAdd(&h[(bw >> 10) & 2047u], 1u);
  }
  __syncthreads();
  if (tid == 0) {
    unsigned int cum = 0;
    for (int b = 2047; b >= 0; --b) {
      unsigned int hb = h[b];
      if (cum + hb >= k1) { sel[1] = (unsigned)b; sel[3] = k1 - cum; break; }
      cum += hb;
    }
  }
  __syncthreads();
  unsigned int b2 = sel[1], k2 = sel[3];
  unsigned int pre = (b1 << 11) | b2;

  for (int i = tid; i < 1024; i += T) h[i] = 0u;
  __syncthreads();
  for (int q = tid; q < NQ; q += T) {
    float4 v = reinterpret_cast<const float4*>(loss)[q];
    unsigned int bx = __float_as_uint(v.x), by = __float_as_uint(v.y);
    unsigned int bz = __float_as_uint(v.z), bw = __float_as_uint(v.w);
    if ((bx >> 10) == pre) atomicAdd(&h[bx & 1023u], 1u);
    if ((by >> 10) == pre) atomicAdd(&h[by & 1023u], 1u);
    if ((bz >> 10) == pre) atomicAdd(&h[bz & 1023u], 1u);
    if ((bw >> 10) == pre) atomicAdd(&h[bw & 1023u], 1u);
  }
  __syncthreads();
  if (tid == 0) {
    unsigned int cum = 0;
    for (int b = 1023; b >= 0; --b) {
      unsigned int hb = h[b];
      if (cum + hb >= k2) { sel[2] = (b1 << 21) | (b2 << 10) | (unsigned)b; break; }
      cum += hb;
    }
  }
  __syncthreads();
  unsigned int vb = sel[2];

  double ls = 0.0; unsigned int lc = 0u;
  for (int q = tid; q < NQ; q += T) {
    float4 v = reinterpret_cast<const float4*>(loss)[q];
    if (__float_as_uint(v.x) > vb) { ls += (double)v.x; ++lc; }
    if (__float_as_uint(v.y) > vb) { ls += (double)v.y; ++lc; }
    if (__float_as_uint(v.z) > vb) { ls += (double)v.z; ++lc; }
    if (__float_as_uint(v.w) > vb) { ls += (double)v.w; ++lc; }
  }
#pragma unroll
  for (int off = 32; off > 0; off >>= 1) {
    ls += __shfl_down(ls, off);
    lc += __shfl_down(lc, off);
  }
  int wid = tid >> 6;
  if ((tid & 63) == 0) { dsp[wid] = ls; dcp[wid] = lc; }
  __syncthreads();
  if (tid == 0) {
    double sumV = 0.0; unsigned int cntV = 0u;
    for (int i = 0; i < 16; ++i) { sumV += dsp[i]; cntV += dcp[i]; }
    float v = __uint_as_float(vb);
    double top = sumV + (double)(KSEL - cntV) * (double)v;
    out[0] = (float)(top / (double)KSEL);
  }
}

extern "C" void kernel_launch(void* const* d_in, const int* in_sizes, int n_in,
                              void* d_out, int out_size, void* d_ws, size_t ws_size,
                              hipStream_t stream) {
  const float* logits = (const float*)d_in[0];
  const int*   labels = (const int*)d_in[1];
  float* out  = (float*)d_out;
  float* loss = (float*)d_ws;                           // 16 MiB per-pixel losses
  Meta*  meta = (Meta*)((char*)d_ws + (size_t)BHW * 4); // metadata after loss array

  k_init        <<<1, 256, 0, stream>>>(meta);
  k_hist_weights<<<GRID_Q, 256, 0, stream>>>(labels, meta);
  k_loss        <<<GRID_Q, 256, 0, stream>>>(logits, labels, loss, meta);
  k_final       <<<1, 1024, 0, stream>>>(loss, meta, out);
}

// Round 9
// 188.682 us; speedup vs baseline: 2.0688x; 1.0658x over previous
//
#include <hip/hip_runtime.h>
#include <math.h>

// Problem constants (fixed shapes from setup_inputs)
#define NCLS   19
#define HW     (512*1024)          // 524288 per-image plane
#define BHW    (8*HW)              // 4194304 pixels
#define NQ     (BHW/4)             // 1048576 quads
#define GRID_Q (NQ/256)            // 4096 blocks (4 px/thread)
#define NSLOT  64                  // partial-sum slots
#define KSEL   262144u             // N_MIN
#define THRESH 0.35667494393873245f

struct Meta {
  double Spart[NSLOT];        // partial sums of losses > THRESH
  unsigned int Kpart[NSLOT];  // partial counts of losses > THRESH
  unsigned int done0;         // last-block counter, k_hist_weights
  unsigned int _pad[3];
  unsigned int counts[32];    // label histogram
  float weights[32];          // ENet class weights
};

// ---------- zero the accumulators ----------
__global__ __launch_bounds__(256) void k_init(Meta* __restrict__ m) {
  unsigned int* p = (unsigned int*)m;
  const int n = (int)(sizeof(Meta) / 4);
  for (int i = threadIdx.x; i < n; i += 256) p[i] = 0u;
}

// ---------- label histogram + ENet weights (last-block fused) ----------
__global__ __launch_bounds__(256) void k_hist_weights(const int* __restrict__ lab,
                                                      Meta* __restrict__ m) {
  __shared__ unsigned int h[32];
  if (threadIdx.x < 32) h[threadIdx.x] = 0u;
  __syncthreads();
  int q = blockIdx.x * 256 + threadIdx.x;       // grid covers NQ exactly
  int4 l = reinterpret_cast<const int4*>(lab)[q];
  atomicAdd(&h[l.x], 1u);
  atomicAdd(&h[l.y], 1u);
  atomicAdd(&h[l.z], 1u);
  atomicAdd(&h[l.w], 1u);
  __syncthreads();
  if (threadIdx.x < 32) {
    unsigned int c = h[threadIdx.x];
    if (c) atomicAdd(&m->counts[threadIdx.x], c);
  }
  __syncthreads();
  if (threadIdx.x == 0) {
    __threadfence();
    unsigned int done = atomicAdd(&m->done0, 1u);
    if (done == GRID_Q - 1u) {
      for (int c = 0; c < NCLS; ++c) {
        unsigned int cnt = atomicAdd(&m->counts[c], 0u);
        float p = (float)cnt * (1.0f / (float)BHW);
        m->weights[c] = 1.0f / logf(1.02f + p);
      }
    }
  }
}

// ---------- fused weighted-CE loss: two-pass, 19 loads in flight ----------
// __launch_bounds__(256, 4): VGPR cap 128 so float4 vals[19] (76 VGPR) stays
// in registers — all 19 stream loads issue back-to-back per wave (19 KB
// outstanding/wave), which is what saturates HBM. (256,8) would cap at 64
// VGPRs and spill; online-softmax variants kept only ~2 loads in flight.
__global__ __launch_bounds__(256, 4) void k_loss(const float* __restrict__ logits,
                                                 const int* __restrict__ lab,
                                                 float* __restrict__ loss,
                                                 Meta* __restrict__ m) {
  __shared__ float w[NCLS];
  __shared__ float sp[4];
  __shared__ unsigned int cp[4];
  if (threadIdx.x < NCLS) w[threadIdx.x] = m->weights[threadIdx.x];
  __syncthreads();

  int q = blockIdx.x * 256 + threadIdx.x;       // quad index, grid covers NQ
  int base = q << 2;
  int b  = base >> 19;                          // / HW (2^19)
  int hw = base & (HW - 1);
  const float* lp = logits + (size_t)b * (NCLS * HW) + hw;
  int4 l4 = reinterpret_cast<const int4*>(lab)[q];

  float4 vals[NCLS];
#pragma unroll
  for (int c = 0; c < NCLS; ++c) {
    vals[c] = *reinterpret_cast<const float4*>(lp);   // independent addresses,
    lp += HW;                                         // all issue before use
  }

  float m0 = vals[0].x, m1 = vals[0].y, m2 = vals[0].z, m3 = vals[0].w;
#pragma unroll
  for (int c = 1; c < NCLS; ++c) {
    m0 = fmaxf(m0, vals[c].x); m1 = fmaxf(m1, vals[c].y);
    m2 = fmaxf(m2, vals[c].z); m3 = fmaxf(m3, vals[c].w);
  }
  float s0 = 0.f, s1 = 0.f, s2 = 0.f, s3 = 0.f;
  float x0 = 0.f, x1 = 0.f, x2 = 0.f, x3 = 0.f;
#pragma unroll
  for (int c = 0; c < NCLS; ++c) {
    float4 v = vals[c];
    s0 += __expf(v.x - m0); s1 += __expf(v.y - m1);
    s2 += __expf(v.z - m2); s3 += __expf(v.w - m3);
    x0 = (c == l4.x) ? v.x : x0;
    x1 = (c == l4.y) ? v.y : x1;
    x2 = (c == l4.z) ? v.z : x2;
    x3 = (c == l4.w) ? v.w : x3;
  }
  float4 o;
  o.x = w[l4.x] * (m0 + logf(s0) - x0);
  o.y = w[l4.y] * (m1 + logf(s1) - x1);
  o.z = w[l4.z] * (m2 + logf(s2) - x2);
  o.w = w[l4.w] * (m3 + logf(s3) - x3);
  reinterpret_cast<float4*>(loss)[q] = o;       // needed only by fallback path

  float ls = 0.f; unsigned int lc = 0u;
  if (o.x > THRESH) { ls += o.x; ++lc; }
  if (o.y > THRESH) { ls += o.y; ++lc; }
  if (o.z > THRESH) { ls += o.z; ++lc; }
  if (o.w > THRESH) { ls += o.w; ++lc; }
#pragma unroll
  for (int off = 32; off > 0; off >>= 1) {
    ls += __shfl_down(ls, off);
    lc += __shfl_down(lc, off);
  }
  int wid = threadIdx.x >> 6;
  if ((threadIdx.x & 63) == 0) { sp[wid] = ls; cp[wid] = lc; }
  __syncthreads();
  if (threadIdx.x == 0) {
    float bs = sp[0] + sp[1] + sp[2] + sp[3];
    unsigned int bc = cp[0] + cp[1] + cp[2] + cp[3];
    int slot = blockIdx.x & (NSLOT - 1);        // 64 contenders/slot
    atomicAdd(&m->Spart[slot], (double)bs);
    atomicAdd(&m->Kpart[slot], bc);
  }
}

// ---------- finalize: common path trivial; rare path = radix select ----------
__global__ __launch_bounds__(1024) void k_final(const float* __restrict__ loss,
                                                Meta* __restrict__ m,
                                                float* __restrict__ out) {
  __shared__ unsigned int h[2048];
  __shared__ unsigned int sel[4];   // b1, b2, vbits, k-remaining
  __shared__ double dsp[16];
  __shared__ unsigned int dcp[16];

  const int T = 1024;
  int tid = threadIdx.x;

  __shared__ unsigned int Ktot_s;
  if (tid == 0) {
    double S = 0.0; unsigned int K = 0u;
    for (int i = 0; i < NSLOT; ++i) { S += m->Spart[i]; K += m->Kpart[i]; }
    Ktot_s = K;
    if (K > KSEL) out[0] = (float)(S / (double)K);  // common path: done
  }
  __syncthreads();
  unsigned int K = Ktot_s;
  if (K > KSEL) return;

  // ---- rare path: exact top-KSEL via 3-level radix select over loss bits ----
  for (int i = tid; i < 2048; i += T) h[i] = 0u;
  __syncthreads();
  for (int q = tid; q < NQ; q += T) {
    float4 v = reinterpret_cast<const float4*>(loss)[q];
    atomicAdd(&h[__float_as_uint(v.x) >> 21], 1u);
    atomicAdd(&h[__float_as_uint(v.y) >> 21], 1u);
    atomicAdd(&h[__float_as_uint(v.z) >> 21], 1u);
    atomicAdd(&h[__float_as_uint(v.w) >> 21], 1u);
  }
  __syncthreads();
  if (tid == 0) {
    unsigned int cum = 0;
    for (int b = 2047; b >= 0; --b) {
      unsigned int hb = h[b];
      if (cum + hb >= KSEL) { sel[0] = (unsigned)b; sel[3] = KSEL - cum; break; }
      cum += hb;
    }
  }
  __syncthreads();
  unsigned int b1 = sel[0], k1 = sel[3];

  for (int i = tid; i < 2048; i += T) h[i] = 0u;
  __syncthreads();
  for (int q = tid; q < NQ; q += T) {
    float4 v = reinterpret_cast<const float4*>(loss)[q];
    unsigned int bx = __float_as_uint(v.x), by = __float_as_uint(v.y);
    unsigned int bz = __float_as_uint(v.z), bw = __float_as_uint(v.w);
    if ((bx >> 21) == b1) atomicAdd(&h[(bx >> 10) & 2047u], 1u);
    if ((by >> 21) == b1) atomicAdd(&h[(by >> 10) & 2047u], 1u);
    if ((bz >> 21) == b1) atomicAdd(&h[(bz >> 10) & 2047u], 1u);
    if ((bw >> 21) == b1) atomicAdd(&h[(bw >> 10) & 2047u], 1u);
  }
  __syncthreads();
  if (tid == 0) {
    unsigned int cum = 0;
    for (int b = 2047; b >= 0; --b) {
      unsigned int hb = h[b];
      if (cum + hb >= k1) { sel[1] = (unsigned)b; sel[3] = k1 - cum; break; }
      cum += hb;
    }
  }
  __syncthreads();
  unsigned int b2 = sel[1], k2 = sel[3];
  unsigned int pre = (b1 << 11) | b2;

  for (int i = tid; i < 1024; i += T) h[i] = 0u;
  __syncthreads();
  for (int q = tid; q < NQ; q += T) {
    float4 v = reinterpret_cast<const float4*>(loss)[q];
    unsigned int bx = __float_as_uint(v.x), by = __float_as_uint(v.y);
    unsigned int bz = __float_as_uint(v.z), bw = __float_as_uint(v.w);
    if ((bx >> 10) == pre) atomicAdd(&h[bx & 1023u], 1u);
    if ((by >> 10) == pre) atomicAdd(&h[by & 1023u], 1u);
    if ((bz >> 10) == pre) atomicAdd(&h[bz & 1023u], 1u);
    if ((bw >> 10) == pre) atomicAdd(&h[bw & 1023u], 1u);
  }
  __syncthreads();
  if (tid == 0) {
    unsigned int cum = 0;
    for (int b = 1023; b >= 0; --b) {
      unsigned int hb = h[b];
      if (cum + hb >= k2) { sel[2] = (b1 << 21) | (b2 << 10) | (unsigned)b; break; }
      cum += hb;
    }
  }
  __syncthreads();
  unsigned int vb = sel[2];

  double ls = 0.0; unsigned int lc = 0u;
  for (int q = tid; q < NQ; q += T) {
    float4 v = reinterpret_cast<const float4*>(loss)[q];
    if (__float_as_uint(v.x) > vb) { ls += (double)v.x; ++lc; }
    if (__float_as_uint(v.y) > vb) { ls += (double)v.y; ++lc; }
    if (__float_as_uint(v.z) > vb) { ls += (double)v.z; ++lc; }
    if (__float_as_uint(v.w) > vb) { ls += (double)v.w; ++lc; }
  }
#pragma unroll
  for (int off = 32; off > 0; off >>= 1) {
    ls += __shfl_down(ls, off);
    lc += __shfl_down(lc, off);
  }
  int wid = tid >> 6;
  if ((tid & 63) == 0) { dsp[wid] = ls; dcp[wid] = lc; }
  __syncthreads();
  if (tid == 0) {
    double sumV = 0.0; unsigned int cntV = 0u;
    for (int i = 0; i < 16; ++i) { sumV += dsp[i]; cntV += dcp[i]; }
    float v = __uint_as_float(vb);
    double top = sumV + (double)(KSEL - cntV) * (double)v;
    out[0] = (float)(top / (double)KSEL);
  }
}

extern "C" void kernel_launch(void* const* d_in, const int* in_sizes, int n_in,
                              void* d_out, int out_size, void* d_ws, size_t ws_size,
                              hipStream_t stream) {
  const float* logits = (const float*)d_in[0];
  const int*   labels = (const int*)d_in[1];
  float* out  = (float*)d_out;
  float* loss = (float*)d_ws;                           // 16 MiB per-pixel losses
  Meta*  meta = (Meta*)((char*)d_ws + (size_t)BHW * 4); // metadata after loss array

  k_init        <<<1, 256, 0, stream>>>(meta);
  k_hist_weights<<<GRID_Q, 256, 0, stream>>>(labels, meta);
  k_loss        <<<GRID_Q, 256, 0, stream>>>(logits, labels, loss, meta);
  k_final       <<<1, 1024, 0, stream>>>(loss, meta, out);
}

// Round 10
// 188.056 us; speedup vs baseline: 2.0757x; 1.0033x over previous
//
#include <hip/hip_runtime.h>
#include <math.h>

// Problem constants (fixed shapes from setup_inputs)
#define NCLS   19
#define HW     (512*1024)          // 524288 per-image plane
#define BHW    (8*HW)              // 4194304 pixels
#define NQ     (BHW/4)             // 1048576 int4 quads (labels/hist)
#define ND     (BHW/2)             // 2097152 float2 duos (loss kernel)
#define GRID_H (NQ/256)            // 4096 blocks, label hist
#define GRID_D (ND/256)            // 8192 blocks, loss (2 px/thread)
#define NSLOT  64                  // partial-sum slots
#define KSEL   262144u             // N_MIN
#define THRESH 0.35667494393873245f

struct Meta {
  double Spart[NSLOT];        // partial sums of losses > THRESH
  unsigned int Kpart[NSLOT];  // partial counts of losses > THRESH
  unsigned int done0;         // last-block counter, k_hist_weights
  unsigned int _pad[3];
  unsigned int counts[32];    // label histogram
  float weights[32];          // ENet class weights
};

// ---------- zero the accumulators ----------
__global__ __launch_bounds__(256) void k_init(Meta* __restrict__ m) {
  unsigned int* p = (unsigned int*)m;
  const int n = (int)(sizeof(Meta) / 4);
  for (int i = threadIdx.x; i < n; i += 256) p[i] = 0u;
}

// ---------- label histogram + ENet weights (last-block fused) ----------
__global__ __launch_bounds__(256) void k_hist_weights(const int* __restrict__ lab,
                                                      Meta* __restrict__ m) {
  __shared__ unsigned int h[32];
  if (threadIdx.x < 32) h[threadIdx.x] = 0u;
  __syncthreads();
  int q = blockIdx.x * 256 + threadIdx.x;       // grid covers NQ exactly
  int4 l = reinterpret_cast<const int4*>(lab)[q];
  atomicAdd(&h[l.x], 1u);
  atomicAdd(&h[l.y], 1u);
  atomicAdd(&h[l.z], 1u);
  atomicAdd(&h[l.w], 1u);
  __syncthreads();
  if (threadIdx.x < 32) {
    unsigned int c = h[threadIdx.x];
    if (c) atomicAdd(&m->counts[threadIdx.x], c);
  }
  __syncthreads();
  if (threadIdx.x == 0) {
    __threadfence();
    unsigned int done = atomicAdd(&m->done0, 1u);
    if (done == GRID_H - 1u) {
      for (int c = 0; c < NCLS; ++c) {
        unsigned int cnt = atomicAdd(&m->counts[c], 0u);
        float p = (float)cnt * (1.0f / (float)BHW);
        m->weights[c] = 1.0f / logf(1.02f + p);
      }
    }
  }
}

// ---------- fused weighted-CE loss: 2 px/thread, float2 vals[19] ----------
// Live set ~70-80 VGPR (38 for vals) — fits the (256,4) 128-VGPR cap with
// margin, so zero spill risk, while keeping 19 independent 8B loads in
// flight per lane (MLP) — the r9 float4 variant may have spilled at 128.
__global__ __launch_bounds__(256, 4) void k_loss(const float* __restrict__ logits,
                                                 const int* __restrict__ lab,
                                                 float* __restrict__ loss,
                                                 Meta* __restrict__ m) {
  __shared__ float w[NCLS];
  __shared__ float sp[4];
  __shared__ unsigned int cp[4];
  if (threadIdx.x < NCLS) w[threadIdx.x] = m->weights[threadIdx.x];
  __syncthreads();

  int d = blockIdx.x * 256 + threadIdx.x;       // duo index, grid covers ND
  int base = d << 1;
  int b  = base >> 19;                          // / HW (2^19)
  int hw = base & (HW - 1);
  const float* lp = logits + (size_t)b * (NCLS * HW) + hw;
  int2 l2 = reinterpret_cast<const int2*>(lab)[d];

  float2 vals[NCLS];
#pragma unroll
  for (int c = 0; c < NCLS; ++c) {
    vals[c] = *reinterpret_cast<const float2*>(lp);   // 19 independent loads
    lp += HW;
  }

  float m0 = vals[0].x, m1 = vals[0].y;
#pragma unroll
  for (int c = 1; c < NCLS; ++c) {
    m0 = fmaxf(m0, vals[c].x);
    m1 = fmaxf(m1, vals[c].y);
  }
  float s0 = 0.f, s1 = 0.f, x0 = 0.f, x1 = 0.f;
#pragma unroll
  for (int c = 0; c < NCLS; ++c) {
    float2 v = vals[c];
    s0 += __expf(v.x - m0);
    s1 += __expf(v.y - m1);
    x0 = (c == l2.x) ? v.x : x0;
    x1 = (c == l2.y) ? v.y : x1;
  }
  float2 o;
  o.x = w[l2.x] * (m0 + logf(s0) - x0);
  o.y = w[l2.y] * (m1 + logf(s1) - x1);
  reinterpret_cast<float2*>(loss)[d] = o;       // needed only by fallback path

  float ls = 0.f; unsigned int lc = 0u;
  if (o.x > THRESH) { ls += o.x; ++lc; }
  if (o.y > THRESH) { ls += o.y; ++lc; }
#pragma unroll
  for (int off = 32; off > 0; off >>= 1) {
    ls += __shfl_down(ls, off);
    lc += __shfl_down(lc, off);
  }
  int wid = threadIdx.x >> 6;
  if ((threadIdx.x & 63) == 0) { sp[wid] = ls; cp[wid] = lc; }
  __syncthreads();
  if (threadIdx.x == 0) {
    float bs = sp[0] + sp[1] + sp[2] + sp[3];
    unsigned int bc = cp[0] + cp[1] + cp[2] + cp[3];
    int slot = blockIdx.x & (NSLOT - 1);        // 128 contenders/slot
    atomicAdd(&m->Spart[slot], (double)bs);
    atomicAdd(&m->Kpart[slot], bc);
  }
}

// ---------- finalize: common path trivial; rare path = radix select ----------
__global__ __launch_bounds__(1024) void k_final(const float* __restrict__ loss,
                                                Meta* __restrict__ m,
                                                float* __restrict__ out) {
  __shared__ unsigned int h[2048];
  __shared__ unsigned int sel[4];   // b1, b2, vbits, k-remaining
  __shared__ double dsp[16];
  __shared__ unsigned int dcp[16];

  const int T = 1024;
  int tid = threadIdx.x;

  __shared__ unsigned int Ktot_s;
  if (tid == 0) {
    double S = 0.0; unsigned int K = 0u;
    for (int i = 0; i < NSLOT; ++i) { S += m->Spart[i]; K += m->Kpart[i]; }
    Ktot_s = K;
    if (K > KSEL) out[0] = (float)(S / (double)K);  // common path: done
  }
  __syncthreads();
  unsigned int K = Ktot_s;
  if (K > KSEL) return;

  // ---- rare path: exact top-KSEL via 3-level radix select over loss bits ----
  for (int i = tid; i < 2048; i += T) h[i] = 0u;
  __syncthreads();
  for (int q = tid; q < NQ; q += T) {
    float4 v = reinterpret_cast<const float4*>(loss)[q];
    atomicAdd(&h[__float_as_uint(v.x) >> 21], 1u);
    atomicAdd(&h[__float_as_uint(v.y) >> 21], 1u);
    atomicAdd(&h[__float_as_uint(v.z) >> 21], 1u);
    atomicAdd(&h[__float_as_uint(v.w) >> 21], 1u);
  }
  __syncthreads();
  if (tid == 0) {
    unsigned int cum = 0;
    for (int b = 2047; b >= 0; --b) {
      unsigned int hb = h[b];
      if (cum + hb >= KSEL) { sel[0] = (unsigned)b; sel[3] = KSEL - cum; break; }
      cum += hb;
    }
  }
  __syncthreads();
  unsigned int b1 = sel[0], k1 = sel[3];

  for (int i = tid; i < 2048; i += T) h[i] = 0u;
  __syncthreads();
  for (int q = tid; q < NQ; q += T) {
    float4 v = reinterpret_cast<const float4*>(loss)[q];
    unsigned int bx = __float_as_uint(v.x), by = __float_as_uint(v.y);
    unsigned int bz = __float_as_uint(v.z), bw = __float_as_uint(v.w);
    if ((bx >> 21) == b1) atomicAdd(&h[(bx >> 10) & 2047u], 1u);
    if ((by >> 21) == b1) atomicAdd(&h[(by >> 10) & 2047u], 1u);
    if ((bz >> 21) == b1) atomicAdd(&h[(bz >> 10) & 2047u], 1u);
    if ((bw >> 21) == b1) atomicAdd(&h[(bw >> 10) & 2047u], 1u);
  }
  __syncthreads();
  if (tid == 0) {
    unsigned int cum = 0;
    for (int b = 2047; b >= 0; --b) {
      unsigned int hb = h[b];
      if (cum + hb >= k1) { sel[1] = (unsigned)b; sel[3] = k1 - cum; break; }
      cum += hb;
    }
  }
  __syncthreads();
  unsigned int b2 = sel[1], k2 = sel[3];
  unsigned int pre = (b1 << 11) | b2;

  for (int i = tid; i < 1024; i += T) h[i] = 0u;
  __syncthreads();
  for (int q = tid; q < NQ; q += T) {
    float4 v = reinterpret_cast<const float4*>(loss)[q];
    unsigned int bx = __float_as_uint(v.x), by = __float_as_uint(v.y);
    unsigned int bz = __float_as_uint(v.z), bw = __float_as_uint(v.w);
    if ((bx >> 10) == pre) atomicAdd(&h[bx & 1023u], 1u);
    if ((by >> 10) == pre) atomicAdd(&h[by & 1023u], 1u);
    if ((bz >> 10) == pre) atomicAdd(&h[bz & 1023u], 1u);
    if ((bw >> 10) == pre) atomicAdd(&h[bw & 1023u], 1u);
  }
  __syncthreads();
  if (tid == 0) {
    unsigned int cum = 0;
    for (int b = 1023; b >= 0; --b) {
      unsigned int hb = h[b];
      if (cum + hb >= k2) { sel[2] = (b1 << 21) | (b2 << 10) | (unsigned)b; break; }
      cum += hb;
    }
  }
  __syncthreads();
  unsigned int vb = sel[2];

  double ls = 0.0; unsigned int lc = 0u;
  for (int q = tid; q < NQ; q += T) {
    float4 v = reinterpret_cast<const float4*>(loss)[q];
    if (__float_as_uint(v.x) > vb) { ls += (double)v.x; ++lc; }
    if (__float_as_uint(v.y) > vb) { ls += (double)v.y; ++lc; }
    if (__float_as_uint(v.z) > vb) { ls += (double)v.z; ++lc; }
    if (__float_as_uint(v.w) > vb) { ls += (double)v.w; ++lc; }
  }
#pragma unroll
  for (int off = 32; off > 0; off >>= 1) {
    ls += __shfl_down(ls, off);
    lc += __shfl_down(lc, off);
  }
  int wid = tid >> 6;
  if ((tid & 63) == 0) { dsp[wid] = ls; dcp[wid] = lc; }
  __syncthreads();
  if (tid == 0) {
    double sumV = 0.0; unsigned int cntV = 0u;
    for (int i = 0; i < 16; ++i) { sumV += dsp[i]; cntV += dcp[i]; }
    float v = __uint_as_float(vb);
    double top = sumV + (double)(KSEL - cntV) * (double)v;
    out[0] = (float)(top / (double)KSEL);
  }
}

extern "C" void kernel_launch(void* const* d_in, const int* in_sizes, int n_in,
                              void* d_out, int out_size, void* d_ws, size_t ws_size,
                              hipStream_t stream) {
  const float* logits = (const float*)d_in[0];
  const int*   labels = (const int*)d_in[1];
  float* out  = (float*)d_out;
  float* loss = (float*)d_ws;                           // 16 MiB per-pixel losses
  Meta*  meta = (Meta*)((char*)d_ws + (size_t)BHW * 4); // metadata after loss array

  k_init        <<<1, 256, 0, stream>>>(meta);
  k_hist_weights<<<GRID_H, 256, 0, stream>>>(labels, meta);
  k_loss        <<<GRID_D, 256, 0, stream>>>(logits, labels, loss, meta);
  k_final       <<<1, 1024, 0, stream>>>(loss, meta, out);
}